// Round 17
// baseline (378.620 us; speedup 1.0000x reference)
//
#include <hip/hip_runtime.h>
#include <hip/hip_fp16.h>
#include <math.h>

typedef unsigned int u32;
typedef unsigned short u16;

#define T_ 16
#define B_ 32
#define S_ 256
#define H_ 256
#define E_ 300
#define V_ 1000

typedef _Float16 h2_t __attribute__((ext_vector_type(2)));
typedef __fp16  fp16v2 __attribute__((ext_vector_type(2)));

__device__ __forceinline__ float fast_tanh(float x) {
    return 1.0f - 2.0f / (__expf(2.0f * x) + 1.0f);
}
__device__ __forceinline__ float fast_sigm(float x) {
    return 1.0f / (1.0f + __expf(-x));
}
__device__ __forceinline__ float bf2f(u16 x) { return __uint_as_float(((u32)x) << 16); }
__device__ __forceinline__ float blo(u32 u) { return __uint_as_float(u << 16); }
__device__ __forceinline__ float bhi(u32 u) { return __uint_as_float(u & 0xffff0000u); }
__device__ __forceinline__ u16 f2bf(float f) {
    u32 u = __float_as_uint(f);
    u32 r = (u + 0x7fffu + ((u >> 16) & 1u)) >> 16;
    return (u16)r;
}
__device__ __forceinline__ h2_t u2h2(u32 u) {
    union { u32 a; h2_t b; } c; c.a = u; return c.b;
}
__device__ __forceinline__ u32 pk2(float a, float b) {
    union { fp16v2 v; u32 u; } c; c.v = __builtin_amdgcn_cvt_pkrtz(a, b); return c.u;
}
__device__ __forceinline__ float dot2f16(u32 w, u32 h, float acc) {
#if __has_builtin(__builtin_amdgcn_fdot2)
    return __builtin_amdgcn_fdot2(u2h2(w), u2h2(h), acc, false);
#else
    h2_t wv = u2h2(w), hv = u2h2(h);
    return acc + (float)wv.x * (float)hv.x + (float)wv.y * (float)hv.y;
#endif
}

// --- fp8 e4m3 encode (prep-side) ---------------------------------------------
__device__ __forceinline__ u32 f2e4m3_1(float f) {
    // manual e4m3fn encode, RNE, clamp (fallback path only)
    u32 b = __float_as_uint(f);
    u32 s = (b >> 31) << 7;
    int e = (int)((b >> 23) & 0xff) - 127;
    u32 m = b & 0x7fffff;
    if (e >= -6) {
        u32 mant = m >> 20;
        u32 rem  = m & 0xfffff;
        if (rem > 0x80000 || (rem == 0x80000 && (mant & 1))) mant++;
        if (mant == 8) { mant = 0; e++; }
        if (e > 8) { e = 8; mant = 7; }
        return s | ((u32)(e + 7) << 3) | mant;
    }
    if (e < -10) return s;
    float q = fabsf(f) * 512.0f;        // subnormal quantum 2^-9
    u32 mant = (u32)(q + 0.5f);
    if (mant > 7) mant = 7;
    return s | mant;
}
__device__ __forceinline__ u32 pack4_e4m3(float a, float b, float c, float d) {
#if __has_builtin(__builtin_amdgcn_cvt_pk_fp8_f32)
    u32 v = (u32)__builtin_amdgcn_cvt_pk_fp8_f32(a, b, 0, false);
    v = (u32)__builtin_amdgcn_cvt_pk_fp8_f32(c, d, (int)v, true);
    return v;
#else
    return f2e4m3_1(a) | (f2e4m3_1(b) << 8) | (f2e4m3_1(c) << 16) | (f2e4m3_1(d) << 24);
#endif
}
// decode 4 e4m3 bytes -> two f16-pairs (cheap: normals exact, zero/subnormal
// approx decode error <= 2^-7 scaled = 5e-4 absolute, ~0.1% of weights)
__device__ __forceinline__ void e4m3q(u32 w, u32& p0, u32& p1) {
    p0 = (((w & 0x00000080u) << 8)  | ((w & 0x0000007fu) << 7)
        | ((w & 0x00008000u) << 16) | ((w & 0x00007f00u) << 15)) + 0x20002000u;
    u32 t = w >> 16;
    p1 = (((t & 0x00000080u) << 8)  | ((t & 0x0000007fu) << 7)
        | ((t & 0x00008000u) << 16) | ((t & 0x00007f00u) << 15)) + 0x20002000u;
}

// ---------------------------------------------------------------------------
// GEMM tile: 64x64, BK=32, 256 threads, 4x4/thread (round-9 proven).
// ---------------------------------------------------------------------------
__device__ void gemm_tile_256(const float* __restrict__ A, const int* __restrict__ gidx,
                              int lda, const float* __restrict__ Bw,
                              const float* __restrict__ bias, float* __restrict__ C,
                              int N, int K, int ldc, int bm, int bn)
{
    __shared__ float As[32][64];
    __shared__ float Bs[32][64];
    const int tid = threadIdx.x;
    const int ty = tid >> 4, tx = tid & 15;
    const int lr = tid >> 2;
    const int lk = (tid & 3) * 8;

    int am = bm + lr;
    int arow = gidx ? gidx[am] : am;
    const float* Ap = A + (size_t)arow * lda;
    int bnr = bn + lr;
    const float* Bp = (bnr < N) ? (Bw + (size_t)bnr * K) : nullptr;

    float acc[4][4] = {};

    for (int k0 = 0; k0 < K; k0 += 32) {
        int kb = k0 + lk;
        float av[8];
        if (kb + 8 <= K) {
            float4 p0 = *(const float4*)(Ap + kb);
            float4 p1 = *(const float4*)(Ap + kb + 4);
            av[0]=p0.x; av[1]=p0.y; av[2]=p0.z; av[3]=p0.w;
            av[4]=p1.x; av[5]=p1.y; av[6]=p1.z; av[7]=p1.w;
        } else {
            #pragma unroll
            for (int j = 0; j < 8; j++) av[j] = (kb + j < K) ? Ap[kb + j] : 0.0f;
        }
        #pragma unroll
        for (int j = 0; j < 8; j++) As[lk + j][lr] = av[j];
        if (Bp && kb + 8 <= K) {
            float4 p0 = *(const float4*)(Bp + kb);
            float4 p1 = *(const float4*)(Bp + kb + 4);
            av[0]=p0.x; av[1]=p0.y; av[2]=p0.z; av[3]=p0.w;
            av[4]=p1.x; av[5]=p1.y; av[6]=p1.z; av[7]=p1.w;
        } else if (Bp) {
            #pragma unroll
            for (int j = 0; j < 8; j++) av[j] = (kb + j < K) ? Bp[kb + j] : 0.0f;
        } else {
            #pragma unroll
            for (int j = 0; j < 8; j++) av[j] = 0.0f;
        }
        #pragma unroll
        for (int j = 0; j < 8; j++) Bs[lk + j][lr] = av[j];
        __syncthreads();
        #pragma unroll
        for (int kk = 0; kk < 32; kk++) {
            float4 a = *(const float4*)&As[kk][ty * 4];
            float4 b = *(const float4*)&Bs[kk][tx * 4];
            acc[0][0] += a.x*b.x; acc[0][1] += a.x*b.y; acc[0][2] += a.x*b.z; acc[0][3] += a.x*b.w;
            acc[1][0] += a.y*b.x; acc[1][1] += a.y*b.y; acc[1][2] += a.y*b.z; acc[1][3] += a.y*b.w;
            acc[2][0] += a.z*b.x; acc[2][1] += a.z*b.y; acc[2][2] += a.z*b.z; acc[2][3] += a.z*b.w;
            acc[3][0] += a.w*b.x; acc[3][1] += a.w*b.y; acc[3][2] += a.w*b.z; acc[3][3] += a.w*b.w;
        }
        __syncthreads();
    }
    #pragma unroll
    for (int i = 0; i < 4; i++) {
        int m = bm + ty * 4 + i;
        #pragma unroll
        for (int j = 0; j < 4; j++) {
            int n = bn + tx * 4 + j;
            if (n < N) C[(size_t)m * ldc + n] = acc[i][j] + bias[n];
        }
    }
}

// ---------------------------------------------------------------------------
// Kernel 1: prep v5 — xproj GEMM tiles + ALL-TILED transposes. 336 blocks.
//   bid <  128       : xproj tile (M=512, N=1024, K=300, gather emb)
//   128 <= bid < 192 : Whh [1024,256] -> Wt8[kq*1024+r] (fp8 e4m3, x16 scale)
//   192 <= bid < 208 : Wd [256,256]   -> Wdt[k*256+h] (fp32)
//   208 <= bid < 336 : W_out [1000,512] -> WoTb[k*1000+v] (bf16)
// ---------------------------------------------------------------------------
__global__ __launch_bounds__(256)
void prep_xproj(const float* __restrict__ emb, const int* __restrict__ tv,
                const float* __restrict__ W_ih, const float* __restrict__ b_ih,
                float* __restrict__ xproj,
                const float* __restrict__ Whh,  u32* __restrict__ Wt8,
                const float* __restrict__ Wd,   float* __restrict__ Wdt,
                const float* __restrict__ W_out, u16* __restrict__ WoTb)
{
    const int bid = blockIdx.x;
    if (bid < 128) {
        gemm_tile_256(emb, tv, E_, W_ih, b_ih, xproj, 1024, E_, 1024,
                      (bid >> 4) * 64, (bid & 15) * 64);
        return;
    }
    __shared__ float tile[64][65];
    const int tid = threadIdx.x;
    const int wv = tid >> 6;      // 0..3
    const int lane = tid & 63;

    if (bid < 192) {
        int t = bid - 128;                       // 0..63
        int r0 = (t >> 2) * 64, k0 = (t & 3) * 64;
        #pragma unroll 4
        for (int j = 0; j < 16; j++) {
            int row = wv * 16 + j;
            tile[row][lane] = Whh[(size_t)(r0 + row) * 256 + k0 + lane];
        }
        __syncthreads();
        #pragma unroll 4
        for (int it = 0; it < 4; it++) {
            int q = wv + 4 * it;                 // k-quad within tile, 0..15
            Wt8[(size_t)((k0 >> 2) + q) * 1024 + r0 + lane] =
                pack4_e4m3(16.0f * tile[lane][4 * q + 0], 16.0f * tile[lane][4 * q + 1],
                           16.0f * tile[lane][4 * q + 2], 16.0f * tile[lane][4 * q + 3]);
        }
    } else if (bid < 208) {
        int t = bid - 192;                       // 0..15
        int h0 = (t >> 2) * 64, k0 = (t & 3) * 64;
        #pragma unroll 4
        for (int j = 0; j < 16; j++) {
            int row = wv * 16 + j;
            tile[row][lane] = Wd[(size_t)(h0 + row) * 256 + k0 + lane];
        }
        __syncthreads();
        #pragma unroll 4
        for (int it = 0; it < 16; it++) {
            int jj = wv + 4 * it;                // 0..63
            Wdt[(size_t)(k0 + jj) * 256 + h0 + lane] = tile[lane][jj];
        }
    } else {
        int t = bid - 208;                       // 0..127
        int v0 = (t >> 3) * 64, k0 = (t & 7) * 64;
        #pragma unroll 4
        for (int j = 0; j < 16; j++) {
            int row = wv * 16 + j;
            int v = v0 + row;
            tile[row][lane] = (v < V_) ? W_out[(size_t)v * 512 + k0 + lane] : 0.0f;
        }
        __syncthreads();
        #pragma unroll 4
        for (int it = 0; it < 16; it++) {
            int jj = wv + 4 * it;
            int v = v0 + lane;
            if (v < V_)
                WoTb[(size_t)(k0 + jj) * V_ + v] = f2bf(tile[lane][jj]);
        }
    }
}

// ---------------------------------------------------------------------------
// Kernel 2: heterogeneous lstm + enc_t.
//   bid < 32 : LSTM scan v8 — fp8(x16) W stream (halves the per-CU L2 ingest
//              floor, the round-16 bottleneck), cheap shift-mask decode to
//              f16-pairs, dot2 accumulate, acc/16 at the end. u32 loads,
//              unroll-2 cap (rounds 6/7 lesson).
//   bid >= 32: enc_t 128x128 tile (round-9 proven) on idle CUs.
// ---------------------------------------------------------------------------
__global__ __launch_bounds__(1024, 4)
void lstm_enct(const float* __restrict__ xproj,   // [T,B,1024]
               const u32*   __restrict__ Wt8,     // [64,1024] fp8 k-quads
               const float* __restrict__ bhh,     // [1024]
               const float* __restrict__ h0, const float* __restrict__ c0,
               float* __restrict__ combined,      // [T,B,512] second half
               float* __restrict__ hT, float* __restrict__ cT,
               const float* __restrict__ enc_raw, // [8192,256]
               const float* __restrict__ We,      // [256,256]
               const float* __restrict__ be,
               float* __restrict__ enct)          // [8192,256]
{
    const int bid = blockIdx.x;
    const int tid = threadIdx.x;
    __shared__ float zs[1024], cs[256];
    __shared__ u32 hp[128];
    __shared__ float As2[32][132];
    __shared__ float Bs2[32][132];

    if (bid < 32) {
        const int b = bid;
        const int r = tid;
        if (tid < 256) {
            float h0v = h0[b * 256 + tid];
            cs[tid] = c0[b * 256 + tid];
            float hpart = __shfl_xor(h0v, 1, 64);
            if (!(tid & 1)) hp[tid >> 1] = pk2(h0v, hpart);
        }
        const float bh = bhh[r];
        const u32* wp = Wt8 + r;
        __syncthreads();

        for (int t = 0; t < T_; t++) {
            float xp = xproj[((size_t)t * B_ + b) * 1024 + r];
            float acc = 0.0f;
            const uint4* hp4 = (const uint4*)hp;
            #pragma unroll 2
            for (int i = 0; i < 32; i++) {
                uint4 hv = hp4[i];                       // 4 h-pairs, broadcast
                u32 wa = wp[(size_t)(2 * i + 0) * 1024]; // k-quad 2i
                u32 wb = wp[(size_t)(2 * i + 1) * 1024]; // k-quad 2i+1
                u32 a0, a1, b0, b1;
                e4m3q(wa, a0, a1);
                e4m3q(wb, b0, b1);
                acc = dot2f16(a0, hv.x, acc);
                acc = dot2f16(a1, hv.y, acc);
                acc = dot2f16(b0, hv.z, acc);
                acc = dot2f16(b1, hv.w, acc);
            }
            zs[r] = xp + bh + acc * 0.0625f;
            __syncthreads();

            if (tid < 256) {
                float ig = fast_sigm(zs[tid]);
                float fg = fast_sigm(zs[256 + tid]);
                float gg = fast_tanh(zs[512 + tid]);
                float og = fast_sigm(zs[768 + tid]);
                float c = fg * cs[tid] + ig * gg;
                float h = og * fast_tanh(c);
                cs[tid] = c;
                combined[((size_t)t * B_ + b) * 512 + 256 + tid] = h;
                if (t == T_ - 1) {
                    hT[b * 256 + tid] = h;
                    cT[b * 256 + tid] = c;
                }
                float hpart = __shfl_xor(h, 1, 64);
                if (!(tid & 1)) hp[tid >> 1] = pk2(h, hpart);
            }
            __syncthreads();
        }
    } else {
        const int tile = bid - 32;
        const int bm = (tile >> 1) * 128;
        const int bn = (tile & 1) * 128;
        const int tx = tid & 31, ty = tid >> 5;
        const int lr = tid >> 3;
        const int lk = (tid & 7) * 4;

        const float* Ap = enc_raw + (size_t)(bm + lr) * 256;
        const float* Bp = We + (size_t)(bn + lr) * 256;
        float acc[4][4] = {};

        for (int k0 = 0; k0 < 256; k0 += 32) {
            float4 a4 = *(const float4*)(Ap + k0 + lk);
            float4 b4 = *(const float4*)(Bp + k0 + lk);
            As2[lk + 0][lr] = a4.x; As2[lk + 1][lr] = a4.y;
            As2[lk + 2][lr] = a4.z; As2[lk + 3][lr] = a4.w;
            Bs2[lk + 0][lr] = b4.x; Bs2[lk + 1][lr] = b4.y;
            Bs2[lk + 2][lr] = b4.z; Bs2[lk + 3][lr] = b4.w;
            __syncthreads();
            #pragma unroll
            for (int kk = 0; kk < 32; kk++) {
                float4 a = *(const float4*)&As2[kk][ty * 4];
                float4 b = *(const float4*)&Bs2[kk][tx * 4];
                acc[0][0] += a.x*b.x; acc[0][1] += a.x*b.y; acc[0][2] += a.x*b.z; acc[0][3] += a.x*b.w;
                acc[1][0] += a.y*b.x; acc[1][1] += a.y*b.y; acc[1][2] += a.y*b.z; acc[1][3] += a.y*b.w;
                acc[2][0] += a.z*b.x; acc[2][1] += a.z*b.y; acc[2][2] += a.z*b.z; acc[2][3] += a.z*b.w;
                acc[3][0] += a.w*b.x; acc[3][1] += a.w*b.y; acc[3][2] += a.w*b.z; acc[3][3] += a.w*b.w;
            }
            __syncthreads();
        }
        #pragma unroll
        for (int i = 0; i < 4; i++) {
            int m = bm + ty * 4 + i;
            #pragma unroll
            for (int j = 0; j < 4; j++) {
                int n = bn + tx * 4 + j;
                enct[(size_t)m * 256 + n] = acc[i][j] + be[n];
            }
        }
    }
}

// ---------------------------------------------------------------------------
// Kernel 3: FUSED tail (round-12/14 proven): 512 threads, XCD swizzle,
// bf16 WoT, dect/ctx split across thread halves, in-LDS logits + softmax.
// ---------------------------------------------------------------------------
__global__ __launch_bounds__(512)
void attn_logits(const float* __restrict__ enct,        // [S,B,H]
                 const float* __restrict__ combined_in, // [T,B,512] (2nd half)
                 const float* __restrict__ Wdt,         // [256,256] k-major
                 const float* __restrict__ bd,
                 const float* __restrict__ enc_raw,     // [S,B,H]
                 const float* __restrict__ wa, const float* __restrict__ ba,
                 const int* __restrict__ lens,
                 const u16* __restrict__ WoTb,          // [512,1000] bf16 k-major
                 const float* __restrict__ b_out,       // [1000]
                 float* __restrict__ ctx_out,           // [B,T,H] (d_out)
                 float* __restrict__ probs)             // [T,B,V] (d_out)
{
    const int bid = blockIdx.x;
    const int b = bid & 31;          // XCD swizzle
    const int t = bid >> 5;
    const int tid = threadIdx.x;
    const int wv = tid >> 6, lane = tid & 63;
    __shared__ float ds[256], was[256], sc[256];
    __shared__ float crow[512];
    __shared__ float tmp2[512];
    __shared__ float lrow[1000];
    __shared__ float red[8], red2[8];

    if (tid < 256) {
        crow[256 + tid] = combined_in[((size_t)t * B_ + b) * 512 + 256 + tid];
        was[tid] = wa[tid];
    }
    const int len = lens[b];
    const float bav = ba[0];
    __syncthreads();

    {
        const int h  = tid & 255;
        const int k0 = (tid >> 8) * 128;
        float acc = 0.0f;
        const float* wp = Wdt + h;
        #pragma unroll 4
        for (int k = k0; k < k0 + 128; k++) acc += wp[(size_t)k * 256] * crow[256 + k];
        tmp2[tid] = acc;
    }
    __syncthreads();
    if (tid < 256) ds[tid] = bd[tid] + tmp2[tid] + tmp2[tid + 256];
    __syncthreads();

    for (int s = wv; s < len; s += 8) {
        const float* er = enct + ((size_t)s * B_ + b) * 256;
        float sum = 0.0f;
        #pragma unroll
        for (int j = 0; j < 4; j++) {
            int h = lane + 64 * j;
            sum += fast_tanh(er[h] + ds[h]) * was[h];
        }
        #pragma unroll
        for (int off = 32; off >= 1; off >>= 1) sum += __shfl_xor(sum, off, 64);
        if (lane == 0) sc[s] = sum + bav;
    }
    __syncthreads();

    float x = (tid < len) ? sc[tid] : -INFINITY;
    float m = x;
    #pragma unroll
    for (int off = 32; off >= 1; off >>= 1) m = fmaxf(m, __shfl_xor(m, off, 64));
    if (lane == 0) red[wv] = m;
    __syncthreads();
    m = red[0];
    #pragma unroll
    for (int i = 1; i < 8; i++) m = fmaxf(m, red[i]);
    float e = __expf(x - m);
    float ssum = e;
    #pragma unroll
    for (int off = 32; off >= 1; off >>= 1) ssum += __shfl_xor(ssum, off, 64);
    if (lane == 0) red2[wv] = ssum;
    __syncthreads();
    ssum = red2[0] + red2[1] + red2[2] + red2[3] + red2[4] + red2[5] + red2[6] + red2[7];
    if (tid < 256) sc[tid] = e / ssum;
    __syncthreads();

    {
        const int h  = tid & 255;
        const int sg = tid >> 8;
        const int mid = (len + 1) >> 1;
        const int s0 = sg ? mid : 0;
        const int s1 = sg ? len : mid;
        float cacc = 0.0f;
        const float* eb = enc_raw + (size_t)b * 256 + h;
        for (int s = s0; s < s1; s++) cacc += sc[s] * eb[(size_t)s * (B_ * H_)];
        tmp2[tid] = cacc;
    }
    __syncthreads();
    if (tid < 256) {
        float ctx = tmp2[tid] + tmp2[tid + 256];
        ctx_out[((size_t)b * T_ + t) * 256 + tid] = ctx;
        crow[tid] = ctx;
    }
    __syncthreads();

    if (tid < 500) {
        const int v0 = tid * 2;
        float a0 = b_out[v0], a1 = b_out[v0 + 1];
        const u32* wp = (const u32*)WoTb + tid;
        #pragma unroll 4
        for (int k = 0; k < 512; k++) {
            float c = crow[k];
            u32 w = wp[(size_t)k * 500];
            a0 += c * blo(w);
            a1 += c * bhi(w);
        }
        lrow[v0] = a0;
        lrow[v0 + 1] = a1;
    }
    __syncthreads();

    float v0v = -INFINITY, v1v = -INFINITY;
    if (tid < 500) { v0v = lrow[tid * 2]; v1v = lrow[tid * 2 + 1]; }
    float mx = fmaxf(v0v, v1v);
    #pragma unroll
    for (int off = 32; off >= 1; off >>= 1) mx = fmaxf(mx, __shfl_xor(mx, off, 64));
    if (lane == 0) red[wv] = mx;
    __syncthreads();
    mx = red[0];
    #pragma unroll
    for (int i = 1; i < 8; i++) mx = fmaxf(mx, red[i]);
    float e0 = __expf(v0v - mx), e1 = __expf(v1v - mx);
    float s2 = e0 + e1;
    #pragma unroll
    for (int off = 32; off >= 1; off >>= 1) s2 += __shfl_xor(s2, off, 64);
    if (lane == 0) red2[wv] = s2;
    __syncthreads();
    s2 = red2[0] + red2[1] + red2[2] + red2[3] + red2[4] + red2[5] + red2[6] + red2[7];
    float inv = 1.0f / s2;
    if (tid < 500) {
        float2 pv = make_float2(e0 * inv, e1 * inv);
        *(float2*)&probs[((size_t)t * B_ + b) * V_ + tid * 2] = pv;
    }
}

extern "C" void kernel_launch(void* const* d_in, const int* in_sizes, int n_in,
                              void* d_out, int out_size, void* d_ws, size_t ws_size,
                              hipStream_t stream) {
    const int*   tv       = (const int*)d_in[0];
    const float* h0       = (const float*)d_in[1];
    const float* c0       = (const float*)d_in[2];
    const float* enc_raw  = (const float*)d_in[3];
    const int*   lens     = (const int*)d_in[4];
    const float* emb      = (const float*)d_in[5];
    const float* W_ih     = (const float*)d_in[6];
    const float* W_hh     = (const float*)d_in[7];
    const float* b_ih     = (const float*)d_in[8];
    const float* b_hh     = (const float*)d_in[9];
    const float* We       = (const float*)d_in[10];
    const float* be       = (const float*)d_in[11];
    const float* Wd       = (const float*)d_in[12];
    const float* bd       = (const float*)d_in[13];
    const float* wa       = (const float*)d_in[14];
    const float* ba       = (const float*)d_in[15];
    const float* W_out    = (const float*)d_in[16];
    const float* b_out    = (const float*)d_in[17];

    // workspace layout (fp32 words; within proven 14.63 MB footprint)
    float* ws       = (float*)d_ws;
    float* enct     = ws;                       // [8192,256]  2,097,152
    float* xproj    = ws + 2097152;             // [512,1024]    524,288
    float* Wdt      = ws + 2621440;             // [256,256]      65,536
    u16*   WoTb     = (u16*)(ws + 2752512);     // [512,1000] bf16
    float* combined = ws + 3264512;             // [512,512]     262,144
    u32*   Wt8      = (u32*)(ws + 3526656);     // [64,1024] fp8 k-quads (65,536 w)

    // d_out layout (fp32): probs [T,B,V], hT, cT, ctx [B,T,H]
    float* out      = (float*)d_out;
    float* probs    = out;
    float* hT       = out + 512000;
    float* cT       = out + 520192;
    float* ctx_out  = out + 528384;

    // 1) xproj GEMM tiles + all-tiled coalesced transposes (Whh -> fp8 x16)
    prep_xproj<<<336, 256, 0, stream>>>(emb, tv, W_ih, b_ih, xproj,
                                        W_hh, Wt8, Wd, Wdt, W_out, WoTb);
    // 2) LSTM v8 (fp8 W stream + dot2) + enc_t GEMM
    lstm_enct<<<160, 1024, 0, stream>>>(xproj, Wt8, b_hh, h0, c0, combined, hT, cT,
                                        enc_raw, We, be, enct);
    // 3) fused attention + logits + vocab softmax
    attn_logits<<<512, 512, 0, stream>>>(enct, combined, Wdt, bd, enc_raw,
                                         wa, ba, lens, WoTb, b_out, ctx_out, probs);
}

// Round 18
// 275.514 us; speedup vs baseline: 1.3742x; 1.3742x over previous
//
#include <hip/hip_runtime.h>
#include <hip/hip_fp16.h>
#include <math.h>

typedef unsigned int u32;
typedef unsigned short u16;

#define T_ 16
#define B_ 32
#define S_ 256
#define H_ 256
#define E_ 300
#define V_ 1000

typedef _Float16 h2_t __attribute__((ext_vector_type(2)));
typedef __fp16  fp16v2 __attribute__((ext_vector_type(2)));

__device__ __forceinline__ float fast_tanh(float x) {
    return 1.0f - 2.0f / (__expf(2.0f * x) + 1.0f);
}
__device__ __forceinline__ float fast_sigm(float x) {
    return 1.0f / (1.0f + __expf(-x));
}
__device__ __forceinline__ float bf2f(u16 x) { return __uint_as_float(((u32)x) << 16); }
__device__ __forceinline__ float blo(u32 u) { return __uint_as_float(u << 16); }
__device__ __forceinline__ float bhi(u32 u) { return __uint_as_float(u & 0xffff0000u); }
__device__ __forceinline__ u16 f2bf(float f) {
    u32 u = __float_as_uint(f);
    u32 r = (u + 0x7fffu + ((u >> 16) & 1u)) >> 16;
    return (u16)r;
}
__device__ __forceinline__ h2_t u2h2(u32 u) {
    union { u32 a; h2_t b; } c; c.a = u; return c.b;
}
__device__ __forceinline__ u32 pk2(float a, float b) {
    union { fp16v2 v; u32 u; } c; c.v = __builtin_amdgcn_cvt_pkrtz(a, b); return c.u;
}
__device__ __forceinline__ float dot2f16(u32 w, u32 h, float acc) {
#if __has_builtin(__builtin_amdgcn_fdot2)
    return __builtin_amdgcn_fdot2(u2h2(w), u2h2(h), acc, false);
#else
    h2_t wv = u2h2(w), hv = u2h2(h);
    return acc + (float)wv.x * (float)hv.x + (float)wv.y * (float)hv.y;
#endif
}

// ---------------------------------------------------------------------------
// GEMM tile: 64x64, BK=32, 256 threads, 4x4/thread (round-9 proven).
// ---------------------------------------------------------------------------
__device__ void gemm_tile_256(const float* __restrict__ A, const int* __restrict__ gidx,
                              int lda, const float* __restrict__ Bw,
                              const float* __restrict__ bias, float* __restrict__ C,
                              int N, int K, int ldc, int bm, int bn)
{
    __shared__ float As[32][64];
    __shared__ float Bs[32][64];
    const int tid = threadIdx.x;
    const int ty = tid >> 4, tx = tid & 15;
    const int lr = tid >> 2;
    const int lk = (tid & 3) * 8;

    int am = bm + lr;
    int arow = gidx ? gidx[am] : am;
    const float* Ap = A + (size_t)arow * lda;
    int bnr = bn + lr;
    const float* Bp = (bnr < N) ? (Bw + (size_t)bnr * K) : nullptr;

    float acc[4][4] = {};

    for (int k0 = 0; k0 < K; k0 += 32) {
        int kb = k0 + lk;
        float av[8];
        if (kb + 8 <= K) {
            float4 p0 = *(const float4*)(Ap + kb);
            float4 p1 = *(const float4*)(Ap + kb + 4);
            av[0]=p0.x; av[1]=p0.y; av[2]=p0.z; av[3]=p0.w;
            av[4]=p1.x; av[5]=p1.y; av[6]=p1.z; av[7]=p1.w;
        } else {
            #pragma unroll
            for (int j = 0; j < 8; j++) av[j] = (kb + j < K) ? Ap[kb + j] : 0.0f;
        }
        #pragma unroll
        for (int j = 0; j < 8; j++) As[lk + j][lr] = av[j];
        if (Bp && kb + 8 <= K) {
            float4 p0 = *(const float4*)(Bp + kb);
            float4 p1 = *(const float4*)(Bp + kb + 4);
            av[0]=p0.x; av[1]=p0.y; av[2]=p0.z; av[3]=p0.w;
            av[4]=p1.x; av[5]=p1.y; av[6]=p1.z; av[7]=p1.w;
        } else if (Bp) {
            #pragma unroll
            for (int j = 0; j < 8; j++) av[j] = (kb + j < K) ? Bp[kb + j] : 0.0f;
        } else {
            #pragma unroll
            for (int j = 0; j < 8; j++) av[j] = 0.0f;
        }
        #pragma unroll
        for (int j = 0; j < 8; j++) Bs[lk + j][lr] = av[j];
        __syncthreads();
        #pragma unroll
        for (int kk = 0; kk < 32; kk++) {
            float4 a = *(const float4*)&As[kk][ty * 4];
            float4 b = *(const float4*)&Bs[kk][tx * 4];
            acc[0][0] += a.x*b.x; acc[0][1] += a.x*b.y; acc[0][2] += a.x*b.z; acc[0][3] += a.x*b.w;
            acc[1][0] += a.y*b.x; acc[1][1] += a.y*b.y; acc[1][2] += a.y*b.z; acc[1][3] += a.y*b.w;
            acc[2][0] += a.z*b.x; acc[2][1] += a.z*b.y; acc[2][2] += a.z*b.z; acc[2][3] += a.z*b.w;
            acc[3][0] += a.w*b.x; acc[3][1] += a.w*b.y; acc[3][2] += a.w*b.z; acc[3][3] += a.w*b.w;
        }
        __syncthreads();
    }
    #pragma unroll
    for (int i = 0; i < 4; i++) {
        int m = bm + ty * 4 + i;
        #pragma unroll
        for (int j = 0; j < 4; j++) {
            int n = bn + tx * 4 + j;
            if (n < N) C[(size_t)m * ldc + n] = acc[i][j] + bias[n];
        }
    }
}

// ---------------------------------------------------------------------------
// Kernel 1: prep v4 (round-16 proven) — xproj GEMM tiles + ALL-TILED
// transposes, one heterogeneous grid, 336 blocks x 256 thr.
//   bid <  128       : xproj tile (M=512, N=1024, K=300, gather emb)
//   128 <= bid < 192 : Whh [1024,256] -> Wt2[kp*1024+r] (f16 pairs)
//   192 <= bid < 208 : Wd [256,256]   -> Wdt[k*256+h] (fp32)
//   208 <= bid < 336 : W_out [1000,512] -> WoTb[k*1000+v] (bf16)
// ---------------------------------------------------------------------------
__global__ __launch_bounds__(256)
void prep_xproj(const float* __restrict__ emb, const int* __restrict__ tv,
                const float* __restrict__ W_ih, const float* __restrict__ b_ih,
                float* __restrict__ xproj,
                const float* __restrict__ Whh,  u32* __restrict__ Wt2,
                const float* __restrict__ Wd,   float* __restrict__ Wdt,
                const float* __restrict__ W_out, u16* __restrict__ WoTb)
{
    const int bid = blockIdx.x;
    if (bid < 128) {
        gemm_tile_256(emb, tv, E_, W_ih, b_ih, xproj, 1024, E_, 1024,
                      (bid >> 4) * 64, (bid & 15) * 64);
        return;
    }
    __shared__ float tile[64][65];
    const int tid = threadIdx.x;
    const int wv = tid >> 6;      // 0..3
    const int lane = tid & 63;

    if (bid < 192) {
        int t = bid - 128;                       // 0..63
        int r0 = (t >> 2) * 64, k0 = (t & 3) * 64;
        #pragma unroll 4
        for (int j = 0; j < 16; j++) {
            int row = wv * 16 + j;
            tile[row][lane] = Whh[(size_t)(r0 + row) * 256 + k0 + lane];
        }
        __syncthreads();
        #pragma unroll 4
        for (int it = 0; it < 8; it++) {
            int jj = wv + 4 * it;                // k-pair within tile, 0..31
            Wt2[(size_t)((k0 >> 1) + jj) * 1024 + r0 + lane] =
                pk2(tile[lane][2 * jj], tile[lane][2 * jj + 1]);
        }
    } else if (bid < 208) {
        int t = bid - 192;                       // 0..15
        int h0 = (t >> 2) * 64, k0 = (t & 3) * 64;
        #pragma unroll 4
        for (int j = 0; j < 16; j++) {
            int row = wv * 16 + j;
            tile[row][lane] = Wd[(size_t)(h0 + row) * 256 + k0 + lane];
        }
        __syncthreads();
        #pragma unroll 4
        for (int it = 0; it < 16; it++) {
            int jj = wv + 4 * it;                // 0..63
            Wdt[(size_t)(k0 + jj) * 256 + h0 + lane] = tile[lane][jj];
        }
    } else {
        int t = bid - 208;                       // 0..127
        int v0 = (t >> 3) * 64, k0 = (t & 7) * 64;
        #pragma unroll 4
        for (int j = 0; j < 16; j++) {
            int row = wv * 16 + j;
            int v = v0 + row;
            tile[row][lane] = (v < V_) ? W_out[(size_t)v * 512 + k0 + lane] : 0.0f;
        }
        __syncthreads();
        #pragma unroll 4
        for (int it = 0; it < 16; it++) {
            int jj = wv + 4 * it;
            int v = v0 + lane;
            if (v < V_)
                WoTb[(size_t)(k0 + jj) * V_ + v] = f2bf(tile[lane][jj]);
        }
    }
}

// ---------------------------------------------------------------------------
// Kernel 2: heterogeneous lstm + enc_t — round-16 config with ONE change:
// inner unroll 2 -> 4 (16 loads in flight). Round-17 falsified the BW model:
// halving W bytes (fp8) HALVED memory-level parallelism and doubled time —
// the loop is latency/MLP-bound, so more in-flight loads is the lever.
// Live set ~40 VGPR, still far under the 64-VGPR spill cliff (rounds 6/7).
//   bid >= 32: enc_t 128x128 tile (round-9 proven) on idle CUs.
// ---------------------------------------------------------------------------
__global__ __launch_bounds__(1024, 4)
void lstm_enct(const float* __restrict__ xproj,   // [T,B,1024]
               const u32*   __restrict__ Wt2,     // [128,1024] f16-pair
               const float* __restrict__ bhh,     // [1024]
               const float* __restrict__ h0, const float* __restrict__ c0,
               float* __restrict__ combined,      // [T,B,512] second half
               float* __restrict__ hT, float* __restrict__ cT,
               const float* __restrict__ enc_raw, // [8192,256]
               const float* __restrict__ We,      // [256,256]
               const float* __restrict__ be,
               float* __restrict__ enct)          // [8192,256]
{
    const int bid = blockIdx.x;
    const int tid = threadIdx.x;
    __shared__ float zs[1024], cs[256];
    __shared__ u32 hp[128];
    __shared__ float As2[32][132];
    __shared__ float Bs2[32][132];

    if (bid < 32) {
        const int b = bid;
        const int r = tid;
        if (tid < 256) {
            float h0v = h0[b * 256 + tid];
            cs[tid] = c0[b * 256 + tid];
            float hpart = __shfl_xor(h0v, 1, 64);
            if (!(tid & 1)) hp[tid >> 1] = pk2(h0v, hpart);
        }
        const float bh = bhh[r];
        const u32* wp = Wt2 + r;
        __syncthreads();

        for (int t = 0; t < T_; t++) {
            float xp = xproj[((size_t)t * B_ + b) * 1024 + r];
            float acc = 0.0f;
            const uint4* hp4 = (const uint4*)hp;
            #pragma unroll 4
            for (int i = 0; i < 32; i++) {
                uint4 hv = hp4[i];                       // 4 k-pairs, broadcast
                u32 w0 = wp[(size_t)(4 * i + 0) * 1024];
                u32 w1 = wp[(size_t)(4 * i + 1) * 1024];
                u32 w2 = wp[(size_t)(4 * i + 2) * 1024];
                u32 w3 = wp[(size_t)(4 * i + 3) * 1024];
                acc = dot2f16(w0, hv.x, acc);
                acc = dot2f16(w1, hv.y, acc);
                acc = dot2f16(w2, hv.z, acc);
                acc = dot2f16(w3, hv.w, acc);
            }
            zs[r] = xp + bh + acc;
            __syncthreads();

            if (tid < 256) {
                float ig = fast_sigm(zs[tid]);
                float fg = fast_sigm(zs[256 + tid]);
                float gg = fast_tanh(zs[512 + tid]);
                float og = fast_sigm(zs[768 + tid]);
                float c = fg * cs[tid] + ig * gg;
                float h = og * fast_tanh(c);
                cs[tid] = c;
                combined[((size_t)t * B_ + b) * 512 + 256 + tid] = h;
                if (t == T_ - 1) {
                    hT[b * 256 + tid] = h;
                    cT[b * 256 + tid] = c;
                }
                float hpart = __shfl_xor(h, 1, 64);
                if (!(tid & 1)) hp[tid >> 1] = pk2(h, hpart);
            }
            __syncthreads();
        }
    } else {
        const int tile = bid - 32;
        const int bm = (tile >> 1) * 128;
        const int bn = (tile & 1) * 128;
        const int tx = tid & 31, ty = tid >> 5;
        const int lr = tid >> 3;
        const int lk = (tid & 7) * 4;

        const float* Ap = enc_raw + (size_t)(bm + lr) * 256;
        const float* Bp = We + (size_t)(bn + lr) * 256;
        float acc[4][4] = {};

        for (int k0 = 0; k0 < 256; k0 += 32) {
            float4 a4 = *(const float4*)(Ap + k0 + lk);
            float4 b4 = *(const float4*)(Bp + k0 + lk);
            As2[lk + 0][lr] = a4.x; As2[lk + 1][lr] = a4.y;
            As2[lk + 2][lr] = a4.z; As2[lk + 3][lr] = a4.w;
            Bs2[lk + 0][lr] = b4.x; Bs2[lk + 1][lr] = b4.y;
            Bs2[lk + 2][lr] = b4.z; Bs2[lk + 3][lr] = b4.w;
            __syncthreads();
            #pragma unroll
            for (int kk = 0; kk < 32; kk++) {
                float4 a = *(const float4*)&As2[kk][ty * 4];
                float4 b = *(const float4*)&Bs2[kk][tx * 4];
                acc[0][0] += a.x*b.x; acc[0][1] += a.x*b.y; acc[0][2] += a.x*b.z; acc[0][3] += a.x*b.w;
                acc[1][0] += a.y*b.x; acc[1][1] += a.y*b.y; acc[1][2] += a.y*b.z; acc[1][3] += a.y*b.w;
                acc[2][0] += a.z*b.x; acc[2][1] += a.z*b.y; acc[2][2] += a.z*b.z; acc[2][3] += a.z*b.w;
                acc[3][0] += a.w*b.x; acc[3][1] += a.w*b.y; acc[3][2] += a.w*b.z; acc[3][3] += a.w*b.w;
            }
            __syncthreads();
        }
        #pragma unroll
        for (int i = 0; i < 4; i++) {
            int m = bm + ty * 4 + i;
            #pragma unroll
            for (int j = 0; j < 4; j++) {
                int n = bn + tx * 4 + j;
                enct[(size_t)m * 256 + n] = acc[i][j] + be[n];
            }
        }
    }
}

// ---------------------------------------------------------------------------
// Kernel 3: FUSED tail (round-12/14 proven): 512 threads, XCD swizzle,
// bf16 WoT, dect/ctx split across thread halves, in-LDS logits + softmax.
// ---------------------------------------------------------------------------
__global__ __launch_bounds__(512)
void attn_logits(const float* __restrict__ enct,        // [S,B,H]
                 const float* __restrict__ combined_in, // [T,B,512] (2nd half)
                 const float* __restrict__ Wdt,         // [256,256] k-major
                 const float* __restrict__ bd,
                 const float* __restrict__ enc_raw,     // [S,B,H]
                 const float* __restrict__ wa, const float* __restrict__ ba,
                 const int* __restrict__ lens,
                 const u16* __restrict__ WoTb,          // [512,1000] bf16 k-major
                 const float* __restrict__ b_out,       // [1000]
                 float* __restrict__ ctx_out,           // [B,T,H] (d_out)
                 float* __restrict__ probs)             // [T,B,V] (d_out)
{
    const int bid = blockIdx.x;
    const int b = bid & 31;          // XCD swizzle
    const int t = bid >> 5;
    const int tid = threadIdx.x;
    const int wv = tid >> 6, lane = tid & 63;
    __shared__ float ds[256], was[256], sc[256];
    __shared__ float crow[512];
    __shared__ float tmp2[512];
    __shared__ float lrow[1000];
    __shared__ float red[8], red2[8];

    if (tid < 256) {
        crow[256 + tid] = combined_in[((size_t)t * B_ + b) * 512 + 256 + tid];
        was[tid] = wa[tid];
    }
    const int len = lens[b];
    const float bav = ba[0];
    __syncthreads();

    {
        const int h  = tid & 255;
        const int k0 = (tid >> 8) * 128;
        float acc = 0.0f;
        const float* wp = Wdt + h;
        #pragma unroll 4
        for (int k = k0; k < k0 + 128; k++) acc += wp[(size_t)k * 256] * crow[256 + k];
        tmp2[tid] = acc;
    }
    __syncthreads();
    if (tid < 256) ds[tid] = bd[tid] + tmp2[tid] + tmp2[tid + 256];
    __syncthreads();

    for (int s = wv; s < len; s += 8) {
        const float* er = enct + ((size_t)s * B_ + b) * 256;
        float sum = 0.0f;
        #pragma unroll
        for (int j = 0; j < 4; j++) {
            int h = lane + 64 * j;
            sum += fast_tanh(er[h] + ds[h]) * was[h];
        }
        #pragma unroll
        for (int off = 32; off >= 1; off >>= 1) sum += __shfl_xor(sum, off, 64);
        if (lane == 0) sc[s] = sum + bav;
    }
    __syncthreads();

    float x = (tid < len) ? sc[tid] : -INFINITY;
    float m = x;
    #pragma unroll
    for (int off = 32; off >= 1; off >>= 1) m = fmaxf(m, __shfl_xor(m, off, 64));
    if (lane == 0) red[wv] = m;
    __syncthreads();
    m = red[0];
    #pragma unroll
    for (int i = 1; i < 8; i++) m = fmaxf(m, red[i]);
    float e = __expf(x - m);
    float ssum = e;
    #pragma unroll
    for (int off = 32; off >= 1; off >>= 1) ssum += __shfl_xor(ssum, off, 64);
    if (lane == 0) red2[wv] = ssum;
    __syncthreads();
    ssum = red2[0] + red2[1] + red2[2] + red2[3] + red2[4] + red2[5] + red2[6] + red2[7];
    if (tid < 256) sc[tid] = e / ssum;
    __syncthreads();

    {
        const int h  = tid & 255;
        const int sg = tid >> 8;
        const int mid = (len + 1) >> 1;
        const int s0 = sg ? mid : 0;
        const int s1 = sg ? len : mid;
        float cacc = 0.0f;
        const float* eb = enc_raw + (size_t)b * 256 + h;
        for (int s = s0; s < s1; s++) cacc += sc[s] * eb[(size_t)s * (B_ * H_)];
        tmp2[tid] = cacc;
    }
    __syncthreads();
    if (tid < 256) {
        float ctx = tmp2[tid] + tmp2[tid + 256];
        ctx_out[((size_t)b * T_ + t) * 256 + tid] = ctx;
        crow[tid] = ctx;
    }
    __syncthreads();

    if (tid < 500) {
        const int v0 = tid * 2;
        float a0 = b_out[v0], a1 = b_out[v0 + 1];
        const u32* wp = (const u32*)WoTb + tid;
        #pragma unroll 4
        for (int k = 0; k < 512; k++) {
            float c = crow[k];
            u32 w = wp[(size_t)k * 500];
            a0 += c * blo(w);
            a1 += c * bhi(w);
        }
        lrow[v0] = a0;
        lrow[v0 + 1] = a1;
    }
    __syncthreads();

    float v0v = -INFINITY, v1v = -INFINITY;
    if (tid < 500) { v0v = lrow[tid * 2]; v1v = lrow[tid * 2 + 1]; }
    float mx = fmaxf(v0v, v1v);
    #pragma unroll
    for (int off = 32; off >= 1; off >>= 1) mx = fmaxf(mx, __shfl_xor(mx, off, 64));
    if (lane == 0) red[wv] = mx;
    __syncthreads();
    mx = red[0];
    #pragma unroll
    for (int i = 1; i < 8; i++) mx = fmaxf(mx, red[i]);
    float e0 = __expf(v0v - mx), e1 = __expf(v1v - mx);
    float s2 = e0 + e1;
    #pragma unroll
    for (int off = 32; off >= 1; off >>= 1) s2 += __shfl_xor(s2, off, 64);
    if (lane == 0) red2[wv] = s2;
    __syncthreads();
    s2 = red2[0] + red2[1] + red2[2] + red2[3] + red2[4] + red2[5] + red2[6] + red2[7];
    float inv = 1.0f / s2;
    if (tid < 500) {
        float2 pv = make_float2(e0 * inv, e1 * inv);
        *(float2*)&probs[((size_t)t * B_ + b) * V_ + tid * 2] = pv;
    }
}

extern "C" void kernel_launch(void* const* d_in, const int* in_sizes, int n_in,
                              void* d_out, int out_size, void* d_ws, size_t ws_size,
                              hipStream_t stream) {
    const int*   tv       = (const int*)d_in[0];
    const float* h0       = (const float*)d_in[1];
    const float* c0       = (const float*)d_in[2];
    const float* enc_raw  = (const float*)d_in[3];
    const int*   lens     = (const int*)d_in[4];
    const float* emb      = (const float*)d_in[5];
    const float* W_ih     = (const float*)d_in[6];
    const float* W_hh     = (const float*)d_in[7];
    const float* b_ih     = (const float*)d_in[8];
    const float* b_hh     = (const float*)d_in[9];
    const float* We       = (const float*)d_in[10];
    const float* be       = (const float*)d_in[11];
    const float* Wd       = (const float*)d_in[12];
    const float* bd       = (const float*)d_in[13];
    const float* wa       = (const float*)d_in[14];
    const float* ba       = (const float*)d_in[15];
    const float* W_out    = (const float*)d_in[16];
    const float* b_out    = (const float*)d_in[17];

    // workspace layout (fp32 words; round-16 proven 14.63 MB footprint)
    float* ws       = (float*)d_ws;
    float* enct     = ws;                       // [8192,256]  2,097,152
    float* xproj    = ws + 2097152;             // [512,1024]    524,288
    float* Wdt      = ws + 2621440;             // [256,256]      65,536
    u16*   WoTb     = (u16*)(ws + 2752512);     // [512,1000] bf16
    float* combined = ws + 3264512;             // [512,512]     262,144
    u32*   Wt2      = (u32*)(ws + 3526656);     // [128,1024] f16-pair

    // d_out layout (fp32): probs [T,B,V], hT, cT, ctx [B,T,H]
    float* out      = (float*)d_out;
    float* probs    = out;
    float* hT       = out + 512000;
    float* cT       = out + 520192;
    float* ctx_out  = out + 528384;

    // 1) xproj GEMM tiles + all-tiled coalesced transposes
    prep_xproj<<<336, 256, 0, stream>>>(emb, tv, W_ih, b_ih, xproj,
                                        W_hh, Wt2, Wd, Wdt, W_out, WoTb);
    // 2) LSTM (f16 dot2, unroll 4 = 16 loads in flight) + enc_t GEMM
    lstm_enct<<<160, 1024, 0, stream>>>(xproj, Wt2, b_hh, h0, c0, combined, hT, cT,
                                        enc_raw, We, be, enct);
    // 3) fused attention + logits + vocab softmax
    attn_logits<<<512, 512, 0, stream>>>(enct, combined, Wdt, bd, enc_raw,
                                         wa, ba, lens, WoTb, b_out, ctx_out, probs);
}